// Round 9
// baseline (485.406 us; speedup 1.0000x reference)
//
#include <hip/hip_runtime.h>
#include <hip/hip_fp16.h>
#include <math.h>

#define N 4096
#define C 512
#define H 128
#define PAD 40  // ushort row pitch for MFMA LDS tiles (80 B: 16B-aligned, 2-way banks)

typedef __attribute__((ext_vector_type(8))) short bf16x8;
typedef __attribute__((ext_vector_type(4))) float f32x4;

// ---------------- helpers ----------------

__device__ inline float wave_reduce_sum(float v) {
#pragma unroll
  for (int m = 32; m; m >>= 1) v += __shfl_xor(v, m);
  return v;
}

__device__ inline float lrelu(float v) { return v > 0.f ? v : 0.01f * v; }

__device__ inline bool better(float v, int j, float w, int k) {
  return (v > w) || (v == w && j < k);
}

__device__ inline void top3_ins(float v, int j, float& v0, int& j0,
                                float& v1, int& j1, float& v2, int& j2) {
  if (better(v, j, v0, j0)) { v2 = v1; j2 = j1; v1 = v0; j1 = j0; v0 = v; j0 = j; }
  else if (better(v, j, v1, j1)) { v2 = v1; j2 = j1; v1 = v; j1 = j; }
  else if (better(v, j, v2, j2)) { v2 = v; j2 = j; }
}

__device__ inline void ins4(float s, int j, float v[4], int jx[4]) {
  if (!better(s, j, v[3], jx[3])) return;
  if (better(s, j, v[0], jx[0])) {
    v[3]=v[2]; jx[3]=jx[2]; v[2]=v[1]; jx[2]=jx[1]; v[1]=v[0]; jx[1]=jx[0];
    v[0]=s; jx[0]=j;
  } else if (better(s, j, v[1], jx[1])) {
    v[3]=v[2]; jx[3]=jx[2]; v[2]=v[1]; jx[2]=jx[1]; v[1]=s; jx[1]=j;
  } else if (better(s, j, v[2], jx[2])) {
    v[3]=v[2]; jx[3]=jx[2]; v[2]=s; jx[2]=j;
  } else {
    v[3]=s; jx[3]=j;
  }
}

__device__ inline unsigned short f2bf(float f) {
  unsigned u = __float_as_uint(f);
  unsigned r = u + 0x7fffu + ((u >> 16) & 1u);
  return (unsigned short)(r >> 16);
}
__device__ inline float bf2f(unsigned short h) {
  return __uint_as_float(((unsigned)h) << 16);
}

// ---------------- split fp32 -> bf16 hi/lo ----------------
__global__ __launch_bounds__(256) void k_split(const float* __restrict__ in,
                                               unsigned short* __restrict__ hi,
                                               unsigned short* __restrict__ lo) {
  int idx = (blockIdx.x * 256 + threadIdx.x) * 4;
  float4 v = *(const float4*)&in[idx];
  float vv[4] = {v.x, v.y, v.z, v.w};
  unsigned short h[4], l[4];
#pragma unroll
  for (int c = 0; c < 4; c++) {
    h[c] = f2bf(vv[c]);
    l[c] = f2bf(vv[c] - bf2f(h[c]));
  }
  uint2 ph = {(unsigned)h[0] | ((unsigned)h[1] << 16),
              (unsigned)h[2] | ((unsigned)h[3] << 16)};
  uint2 pl = {(unsigned)l[0] | ((unsigned)l[1] << 16),
              (unsigned)l[2] | ((unsigned)l[3] << 16)};
  *(uint2*)&hi[idx] = ph;
  *(uint2*)&lo[idx] = pl;
}

// transpose + split: in [R,128] fp32 -> thi/tlo [128,R] ushort
__global__ __launch_bounds__(256) void k_tsplit(const float* __restrict__ in,
                                                unsigned short* __restrict__ thi,
                                                unsigned short* __restrict__ tlo,
                                                int R) {
  __shared__ float tile[32][132];
  int r0 = blockIdx.x * 32, tid = threadIdx.x;
#pragma unroll
  for (int q = 0; q < 4; q++) {
    int f = q * 256 + tid;
    int row = f >> 5, ch = f & 31;
    *(float4*)&tile[row][ch * 4] = *(const float4*)&in[(size_t)(r0 + row) * 128 + ch * 4];
  }
  __syncthreads();
  int c = tid & 127, half = tid >> 7;
  unsigned short hh[16], ll[16];
#pragma unroll
  for (int rr = 0; rr < 16; rr++) {
    float v = tile[half * 16 + rr][c];
    hh[rr] = f2bf(v);
    ll[rr] = f2bf(v - bf2f(hh[rr]));
  }
  size_t off = (size_t)c * R + r0 + half * 16;
  uint4 ph0 = {(unsigned)hh[0] | ((unsigned)hh[1] << 16), (unsigned)hh[2] | ((unsigned)hh[3] << 16),
               (unsigned)hh[4] | ((unsigned)hh[5] << 16), (unsigned)hh[6] | ((unsigned)hh[7] << 16)};
  uint4 ph1 = {(unsigned)hh[8] | ((unsigned)hh[9] << 16), (unsigned)hh[10] | ((unsigned)hh[11] << 16),
               (unsigned)hh[12] | ((unsigned)hh[13] << 16), (unsigned)hh[14] | ((unsigned)hh[15] << 16)};
  uint4 pl0 = {(unsigned)ll[0] | ((unsigned)ll[1] << 16), (unsigned)ll[2] | ((unsigned)ll[3] << 16),
               (unsigned)ll[4] | ((unsigned)ll[5] << 16), (unsigned)ll[6] | ((unsigned)ll[7] << 16)};
  uint4 pl1 = {(unsigned)ll[8] | ((unsigned)ll[9] << 16), (unsigned)ll[10] | ((unsigned)ll[11] << 16),
               (unsigned)ll[12] | ((unsigned)ll[13] << 16), (unsigned)ll[14] | ((unsigned)ll[15] << 16)};
  *(uint4*)&thi[off] = ph0; *(uint4*)&thi[off + 8] = ph1;
  *(uint4*)&tlo[off] = pl0; *(uint4*)&tlo[off + 8] = pl1;
}

// ---------------- small kernels ----------------

__global__ __launch_bounds__(64) void k_colsum_s2c(
    const float* __restrict__ cm, const float* __restrict__ mv,
    float* __restrict__ colsum_c) {
  int c = blockIdx.x * 64 + threadIdx.x;
  int i0 = blockIdx.y * 256;
  float acc = 0.f;
  for (int i = i0; i < i0 + 256; i++) acc += cm[(size_t)i * C + c] * mv[i];
  atomicAdd(&colsum_c[c], acc);
}

__global__ __launch_bounds__(64) void k_valid1(const float* __restrict__ hid,
                                               float* __restrict__ valid1) {
  int c = blockIdx.x, t = threadIdx.x;
  float s = hid[(size_t)c * H + t] + hid[(size_t)c * H + 64 + t];
  s = wave_reduce_sum(s);
  if (t == 0) valid1[c] = (s != 0.f) ? 1.f : 0.f;
}

__global__ __launch_bounds__(64) void k_rownorm128(const float* __restrict__ A,
                                                   float* __restrict__ nrm) {
  int r = blockIdx.x, t = threadIdx.x;
  float a = A[(size_t)r * H + t], b = A[(size_t)r * H + 64 + t];
  float ss = wave_reduce_sum(a * a + b * b);
  if (t == 0) nrm[r] = sqrtf(ss);
}

__global__ __launch_bounds__(256) void k_colstats(const float* __restrict__ sc,
                                                  float* __restrict__ colmax,
                                                  float* __restrict__ colsum) {
  __shared__ float red[256];
  int c = blockIdx.x, t = threadIdx.x;
  float v[16];
  float m = -3e38f;
#pragma unroll
  for (int q = 0; q < 16; q++) {
    v[q] = sc[(size_t)(q * 256 + t) * C + c];
    m = fmaxf(m, v[q]);
  }
  red[t] = m; __syncthreads();
  for (int s = 128; s; s >>= 1) { if (t < s) red[t] = fmaxf(red[t], red[t + s]); __syncthreads(); }
  m = red[0]; __syncthreads();
  float sum = 0.f;
#pragma unroll
  for (int q = 0; q < 16; q++) sum += __expf(v[q] - m);
  red[t] = sum; __syncthreads();
  for (int s = 128; s; s >>= 1) { if (t < s) red[t] += red[t + s]; __syncthreads(); }
  if (t == 0) { colmax[c] = m; colsum[c] = red[0]; }
}

// row softmax of cos-sim -> bf16 hi/lo pairs
__global__ __launch_bounds__(256) void k_cs_softmax(
    const float* __restrict__ sc, const float* __restrict__ xnorm,
    const float* __restrict__ hnorm, const float* __restrict__ valid1,
    unsigned short* __restrict__ cshi, unsigned short* __restrict__ cslo) {
  __shared__ float red[256];
  int i = blockIdx.x, t = threadIdx.x;
  float xn = xnorm[i];
  float r0 = sc[(size_t)i * C + t], r1 = sc[(size_t)i * C + 256 + t];
  float d0 = xn * hnorm[t], d1 = xn * hnorm[256 + t];
  float c0 = r0 / (d0 == 0.f ? 1.f : d0);
  float c1 = r1 / (d1 == 0.f ? 1.f : d1);
  float s0 = (valid1[t] != 0.f) ? c0 : -3e38f;
  float s1 = (valid1[256 + t] != 0.f) ? c1 : -3e38f;
  red[t] = fmaxf(s0, s1); __syncthreads();
  for (int s = 128; s; s >>= 1) { if (t < s) red[t] = fmaxf(red[t], red[t + s]); __syncthreads(); }
  float m = red[0]; __syncthreads();
  float p0 = (s0 > -1e37f) ? __expf(s0 - m) : 0.f;
  float p1 = (s1 > -1e37f) ? __expf(s1 - m) : 0.f;
  red[t] = p0 + p1; __syncthreads();
  for (int s = 128; s; s >>= 1) { if (t < s) red[t] += red[t + s]; __syncthreads(); }
  float inv = 1.f / red[0];
  float a = p0 * inv, b = p1 * inv;
  unsigned short ha = f2bf(a), hb = f2bf(b);
  cshi[(size_t)i * C + t] = ha;
  cslo[(size_t)i * C + t] = f2bf(a - bf2f(ha));
  cshi[(size_t)i * C + 256 + t] = hb;
  cslo[(size_t)i * C + 256 + t] = f2bf(b - bf2f(hb));
}

// hhat + pairs + diag value
__global__ __launch_bounds__(64) void k_hhat(const float* __restrict__ h,
                                             float* __restrict__ hhat,
                                             unsigned short* __restrict__ hhi,
                                             unsigned short* __restrict__ hlo,
                                             float* __restrict__ diagv) {
  int i = blockIdx.x, t = threadIdx.x;
  float a = h[(size_t)i * H + t], b = h[(size_t)i * H + 64 + t];
  float ss = wave_reduce_sum(a * a + b * b);
  float hn = sqrtf(ss);
  float den = hn * hn;
  float dg = (den == 0.f) ? 0.f : ss / den;
  float inv = (ss > 0.f) ? (1.f / hn) : 1.f;
  float va = a * inv, vb = b * inv;
  hhat[(size_t)i * H + t] = va;
  hhat[(size_t)i * H + 64 + t] = vb;
  unsigned short ha = f2bf(va), hb = f2bf(vb);
  hhi[(size_t)i * H + t] = ha;
  hlo[(size_t)i * H + t] = f2bf(va - bf2f(ha));
  hhi[(size_t)i * H + 64 + t] = hb;
  hlo[(size_t)i * H + 64 + t] = f2bf(vb - bf2f(hb));
  if (t == 0) diagv[i] = dg;
}

// finalize hidden2 + h2hat pairs + valid2f
__global__ __launch_bounds__(64) void k_fin_hidden2(
    const float* __restrict__ h, const float* __restrict__ diagv,
    const float* __restrict__ colsum_m, float* __restrict__ hidden2,
    unsigned short* __restrict__ h2hi, unsigned short* __restrict__ h2lo,
    float* __restrict__ valid2f) {
  int j = blockIdx.x, t = threadIdx.x;
  float add = (colsum_m[j] != 0.f) ? diagv[j] : 0.f;
  float a = hidden2[(size_t)j * H + t] + add * h[(size_t)j * H + t];
  float b = hidden2[(size_t)j * H + 64 + t] + add * h[(size_t)j * H + 64 + t];
  float s = a + b, ss = a * a + b * b;
#pragma unroll
  for (int m = 32; m; m >>= 1) { s += __shfl_xor(s, m); ss += __shfl_xor(ss, m); }
  bool valid = (s != 0.f);
  a = valid ? a : 0.f; b = valid ? b : 0.f;
  hidden2[(size_t)j * H + t] = a;
  hidden2[(size_t)j * H + 64 + t] = b;
  float inv = (valid && ss > 0.f) ? (1.f / sqrtf(ss)) : 1.f;
  float va = a * inv, vb = b * inv;
  unsigned short ha = f2bf(va), hb = f2bf(vb);
  h2hi[(size_t)j * H + t] = ha;
  h2lo[(size_t)j * H + t] = f2bf(va - bf2f(ha));
  h2hi[(size_t)j * H + 64 + t] = hb;
  h2lo[(size_t)j * H + 64 + t] = f2bf(vb - bf2f(hb));
  if (t == 0) valid2f[j] = valid ? 1.f : 0.f;
}

__global__ __launch_bounds__(64) void k_final(const float* __restrict__ ai,
                                              const float* __restrict__ Wout,
                                              const float* __restrict__ bout,
                                              float* __restrict__ out) {
  int i = blockIdx.x, t = threadIdx.x;
  float s = ai[(size_t)i * H + t] * Wout[t] + ai[(size_t)i * H + 64 + t] * Wout[64 + t];
  s = wave_reduce_sum(s);
  if (t == 0) out[i] = s + bout[0];
}

// ---------------- bf16x3 MFMA NT GEMM: A[M,128] @ B[Nn,128]^T ----------------
// EPI 0: fp32 store; 3: E=exp(s-1) masked -> single bf16 (ehi) + row-sum atomics
template <int EPI>
__global__ __launch_bounds__(256) void k_mfma_nt(
    const unsigned short* __restrict__ Ahi, const unsigned short* __restrict__ Alo,
    const unsigned short* __restrict__ Bhi, const unsigned short* __restrict__ Blo,
    const float* __restrict__ validn, float* __restrict__ out,
    unsigned short* __restrict__ ehi, float* __restrict__ lsum, int Nn) {
  __shared__ __align__(16) unsigned short sAh[128 * PAD];
  __shared__ __align__(16) unsigned short sAl[128 * PAD];
  __shared__ __align__(16) unsigned short sBh[128 * PAD];
  __shared__ __align__(16) unsigned short sBl[128 * PAD];
  int tid = threadIdx.x;
  int bm = blockIdx.y * 128, bn = blockIdx.x * 128;
  int lane = tid & 63, w = tid >> 6;
  int wm = (w & 1) * 64, wn = (w >> 1) * 64;
  int l15 = lane & 15, quad = lane >> 4;
  f32x4 zero = {0.f, 0.f, 0.f, 0.f};
  f32x4 acc[4][4];
#pragma unroll
  for (int mt = 0; mt < 4; mt++)
#pragma unroll
    for (int nt = 0; nt < 4; nt++) acc[mt][nt] = zero;

  for (int kt = 0; kt < 128; kt += 32) {
#pragma unroll
    for (int q = 0; q < 2; q++) {
      int f = tid * 2 + q;
      int row = f >> 2, ch = f & 3;
      size_t ga = (size_t)(bm + row) * 128 + kt + ch * 8;
      size_t gb = (size_t)(bn + row) * 128 + kt + ch * 8;
      int ls = row * PAD + ch * 8;
      *(uint4*)&sAh[ls] = *(const uint4*)&Ahi[ga];
      *(uint4*)&sAl[ls] = *(const uint4*)&Alo[ga];
      *(uint4*)&sBh[ls] = *(const uint4*)&Bhi[gb];
      *(uint4*)&sBl[ls] = *(const uint4*)&Blo[gb];
    }
    __syncthreads();
    bf16x8 ah[4], al[4], bh[4], bl[4];
#pragma unroll
    for (int t = 0; t < 4; t++) {
      int ar = (wm + t * 16 + l15) * PAD + quad * 8;
      ah[t] = *(const bf16x8*)&sAh[ar];
      al[t] = *(const bf16x8*)&sAl[ar];
      int br = (wn + t * 16 + l15) * PAD + quad * 8;
      bh[t] = *(const bf16x8*)&sBh[br];
      bl[t] = *(const bf16x8*)&sBl[br];
    }
#pragma unroll
    for (int mt = 0; mt < 4; mt++)
#pragma unroll
      for (int nt = 0; nt < 4; nt++) {
        acc[mt][nt] = __builtin_amdgcn_mfma_f32_16x16x32_bf16(ah[mt], bh[nt], acc[mt][nt], 0, 0, 0);
        acc[mt][nt] = __builtin_amdgcn_mfma_f32_16x16x32_bf16(ah[mt], bl[nt], acc[mt][nt], 0, 0, 0);
        acc[mt][nt] = __builtin_amdgcn_mfma_f32_16x16x32_bf16(al[mt], bh[nt], acc[mt][nt], 0, 0, 0);
      }
    __syncthreads();
  }
  if (EPI == 3) {
    float vm[4];
#pragma unroll
    for (int nt = 0; nt < 4; nt++) vm[nt] = validn[bn + wn + nt * 16 + l15];
#pragma unroll
    for (int mt = 0; mt < 4; mt++) {
#pragma unroll
      for (int rg = 0; rg < 4; rg++) {
        int row = bm + wm + mt * 16 + quad * 4 + rg;
        float rsum = 0.f;
#pragma unroll
        for (int nt = 0; nt < 4; nt++) {
          int col = bn + wn + nt * 16 + l15;
          float e = (vm[nt] != 0.f) ? __expf(acc[mt][nt][rg] - 1.f) : 0.f;
          rsum += e;
          ehi[(size_t)row * N + col] = f2bf(e);
        }
#pragma unroll
        for (int d = 1; d < 16; d <<= 1) rsum += __shfl_xor(rsum, d);
        if (l15 == 0) atomicAdd(&lsum[row], rsum);
      }
    }
  } else {
#pragma unroll
    for (int mt = 0; mt < 4; mt++) {
#pragma unroll
      for (int nt = 0; nt < 4; nt++) {
        int col = bn + wn + nt * 16 + l15;
#pragma unroll
        for (int rg = 0; rg < 4; rg++) {
          int row = bm + wm + mt * 16 + quad * 4 + rg;
          out[(size_t)row * Nn + col] = acc[mt][nt][rg];
        }
      }
    }
  }
}

// ---------------- fused S + per-chunk top-4: candidates, no S store ----------
// grid (N/128 jb, N/128 bm). chunk = jb*2 + wave-col-half (64 chunks of 64 cols)
__global__ __launch_bounds__(256) void k_mfma_top(
    const unsigned short* __restrict__ Ahi, const unsigned short* __restrict__ Alo,
    float* __restrict__ candv, int* __restrict__ candi) {
  __shared__ __align__(16) unsigned short sAh[128 * PAD];
  __shared__ __align__(16) unsigned short sAl[128 * PAD];
  __shared__ __align__(16) unsigned short sBh[128 * PAD];
  __shared__ __align__(16) unsigned short sBl[128 * PAD];
  int tid = threadIdx.x;
  int bm = blockIdx.y * 128, bn = blockIdx.x * 128;
  int lane = tid & 63, w = tid >> 6;
  int wm = (w & 1) * 64, wn = (w >> 1) * 64;
  int l15 = lane & 15, quad = lane >> 4;
  f32x4 zero = {0.f, 0.f, 0.f, 0.f};
  f32x4 acc[4][4];
#pragma unroll
  for (int mt = 0; mt < 4; mt++)
#pragma unroll
    for (int nt = 0; nt < 4; nt++) acc[mt][nt] = zero;

  for (int kt = 0; kt < 128; kt += 32) {
#pragma unroll
    for (int q = 0; q < 2; q++) {
      int f = tid * 2 + q;
      int row = f >> 2, ch = f & 3;
      size_t ga = (size_t)(bm + row) * 128 + kt + ch * 8;
      size_t gb = (size_t)(bn + row) * 128 + kt + ch * 8;
      int ls = row * PAD + ch * 8;
      *(uint4*)&sAh[ls] = *(const uint4*)&Ahi[ga];
      *(uint4*)&sAl[ls] = *(const uint4*)&Alo[ga];
      *(uint4*)&sBh[ls] = *(const uint4*)&Ahi[gb];
      *(uint4*)&sBl[ls] = *(const uint4*)&Alo[gb];
    }
    __syncthreads();
    bf16x8 ah[4], al[4], bh[4], bl[4];
#pragma unroll
    for (int t = 0; t < 4; t++) {
      int ar = (wm + t * 16 + l15) * PAD + quad * 8;
      ah[t] = *(const bf16x8*)&sAh[ar];
      al[t] = *(const bf16x8*)&sAl[ar];
      int br = (wn + t * 16 + l15) * PAD + quad * 8;
      bh[t] = *(const bf16x8*)&sBh[br];
      bl[t] = *(const bf16x8*)&sBl[br];
    }
#pragma unroll
    for (int mt = 0; mt < 4; mt++)
#pragma unroll
      for (int nt = 0; nt < 4; nt++) {
        acc[mt][nt] = __builtin_amdgcn_mfma_f32_16x16x32_bf16(ah[mt], bh[nt], acc[mt][nt], 0, 0, 0);
        acc[mt][nt] = __builtin_amdgcn_mfma_f32_16x16x32_bf16(ah[mt], bl[nt], acc[mt][nt], 0, 0, 0);
        acc[mt][nt] = __builtin_amdgcn_mfma_f32_16x16x32_bf16(al[mt], bh[nt], acc[mt][nt], 0, 0, 0);
      }
    __syncthreads();
  }
  int chunk = blockIdx.x * 2 + (wn >> 6);
#pragma unroll
  for (int mt = 0; mt < 4; mt++) {
#pragma unroll
    for (int rg = 0; rg < 4; rg++) {
      int row = bm + wm + mt * 16 + quad * 4 + rg;
      float v[4] = {-3e38f, -3e38f, -3e38f, -3e38f};
      int jx[4] = {0x7fffffff, 0x7fffffff, 0x7fffffff, 0x7fffffff};
#pragma unroll
      for (int nt = 0; nt < 4; nt++) {
        int col = bn + wn + nt * 16 + l15;
        float s = (col == row) ? 0.f : acc[mt][nt][rg];  // ref zeroes diagonal
        ins4(s, col, v, jx);
      }
#pragma unroll
      for (int d = 1; d < 16; d <<= 1) {
        float fv[4]; int fj[4];
#pragma unroll
        for (int c = 0; c < 4; c++) { fv[c] = __shfl_xor(v[c], d); fj[c] = __shfl_xor(jx[c], d); }
#pragma unroll
        for (int c = 0; c < 4; c++) ins4(fv[c], fj[c], v, jx);
      }
      if (l15 == 0) {
#pragma unroll
        for (int s = 0; s < 4; s++) {
          size_t base = (size_t)(chunk * 4 + s) * N + row;
          candv[base] = v[s];
          candi[base] = jx[s];
        }
      }
    }
  }
}

// merge 64 chunk top-4 sets -> exact fp32 rescore -> top3
__global__ __launch_bounds__(256) void k_merge4(
    const float* __restrict__ candv, const int* __restrict__ candi,
    const float* __restrict__ hhat, float* __restrict__ mtv,
    int* __restrict__ mtj) {
  int i = blockIdx.x * 4 + (threadIdx.x >> 6);
  int lane = threadIdx.x & 63;
  float v[4] = {-3e38f, -3e38f, -3e38f, -3e38f};
  int jx[4] = {0x7fffffff, 0x7fffffff, 0x7fffffff, 0x7fffffff};
#pragma unroll
  for (int t = 0; t < 4; t++) {
    int c = t * 64 + lane;
    float cv = candv[(size_t)c * N + i];
    int cj = candi[(size_t)c * N + i];
    ins4(cv, cj, v, jx);
  }
#pragma unroll
  for (int d = 1; d < 64; d <<= 1) {
    float fv[4]; int fj[4];
#pragma unroll
    for (int c = 0; c < 4; c++) { fv[c] = __shfl_xor(v[c], d); fj[c] = __shfl_xor(jx[c], d); }
#pragma unroll
    for (int c = 0; c < 4; c++) ins4(fv[c], fj[c], v, jx);
  }
  const float* hi = &hhat[(size_t)i * H];
  float b0 = -3e38f, b1 = -3e38f, b2 = -3e38f;
  int q0 = 0, q1 = 0, q2 = 0;
#pragma unroll
  for (int c = 0; c < 4; c++) {
    int j = jx[c];
    float s;
    if (j == i) {
      s = 0.f;
    } else {
      const float* hj = &hhat[(size_t)j * H];
      float p = hi[lane] * hj[lane] + hi[lane + 64] * hj[lane + 64];
      s = wave_reduce_sum(p);
    }
    top3_ins(s, j, b0, q0, b1, q1, b2, q2);
  }
  if (lane == 0) {
    mtv[i * 3 + 0] = b0; mtv[i * 3 + 1] = b1; mtv[i * 3 + 2] = b2;
    mtj[i * 3 + 0] = q0; mtj[i * 3 + 1] = q1; mtj[i * 3 + 2] = q2;
  }
}

// ---------------- bf16 MFMA KN GEMM (split-K): partial[z] = A @ B ------------
// ALO=1: A has hi/lo pairs (3 mfma); ALO=0: A single bf16 (2 mfma)
template <int ALO>
__global__ __launch_bounds__(256) void k_mfma_kn(
    const unsigned short* __restrict__ Ahi, const unsigned short* __restrict__ Alo,
    const unsigned short* __restrict__ Bthi, const unsigned short* __restrict__ Btlo,
    float* __restrict__ partial, int lda, int KC) {
  __shared__ __align__(16) unsigned short sAh[128 * PAD];
  __shared__ __align__(16) unsigned short sAl[128 * PAD];
  __shared__ __align__(16) unsigned short sBh[128 * PAD];
  __shared__ __align__(16) unsigned short sBl[128 * PAD];
  int tid = threadIdx.x;
  int bm = blockIdx.y * 128;
  int k0 = blockIdx.z * KC;
  int lane = tid & 63, w = tid >> 6;
  int wm = (w & 1) * 64, wn = (w >> 1) * 64;
  int l15 = lane & 15, quad = lane >> 4;
  f32x4 zero = {0.f, 0.f, 0.f, 0.f};
  f32x4 acc[4][4];
#pragma unroll
  for (int mt = 0; mt < 4; mt++)
#pragma unroll
    for (int nt = 0; nt < 4; nt++) acc[mt][nt] = zero;

  for (int kt = 0; kt < KC; kt += 32) {
#pragma unroll
    for (int q = 0; q < 2; q++) {
      int f = tid * 2 + q;
      int row = f >> 2, ch = f & 3;
      size_t ga = (size_t)(bm + row) * lda + k0 + kt + ch * 8;
      size_t gb = (size_t)row * lda + k0 + kt + ch * 8;
      int ls = row * PAD + ch * 8;
      *(uint4*)&sAh[ls] = *(const uint4*)&Ahi[ga];
      if (ALO) *(uint4*)&sAl[ls] = *(const uint4*)&Alo[ga];
      *(uint4*)&sBh[ls] = *(const uint4*)&Bthi[gb];
      *(uint4*)&sBl[ls] = *(const uint4*)&Btlo[gb];
    }
    __syncthreads();
    bf16x8 ah[4], al[4], bh[4], bl[4];
#pragma unroll
    for (int t = 0; t < 4; t++) {
      int ar = (wm + t * 16 + l15) * PAD + quad * 8;
      ah[t] = *(const bf16x8*)&sAh[ar];
      if (ALO) al[t] = *(const bf16x8*)&sAl[ar];
      int br = (wn + t * 16 + l15) * PAD + quad * 8;
      bh[t] = *(const bf16x8*)&sBh[br];
      bl[t] = *(const bf16x8*)&sBl[br];
    }
#pragma unroll
    for (int mt = 0; mt < 4; mt++)
#pragma unroll
      for (int nt = 0; nt < 4; nt++) {
        acc[mt][nt] = __builtin_amdgcn_mfma_f32_16x16x32_bf16(ah[mt], bh[nt], acc[mt][nt], 0, 0, 0);
        acc[mt][nt] = __builtin_amdgcn_mfma_f32_16x16x32_bf16(ah[mt], bl[nt], acc[mt][nt], 0, 0, 0);
        if (ALO)
          acc[mt][nt] = __builtin_amdgcn_mfma_f32_16x16x32_bf16(al[mt], bh[nt], acc[mt][nt], 0, 0, 0);
      }
    __syncthreads();
  }
  float* pp = partial + (size_t)blockIdx.z * N * 128;
#pragma unroll
  for (int mt = 0; mt < 4; mt++)
#pragma unroll
    for (int nt = 0; nt < 4; nt++) {
      int col = wn + nt * 16 + l15;
#pragma unroll
      for (int rg = 0; rg < 4; rg++) {
        int row = bm + wm + mt * 16 + quad * 4 + rg;
        pp[(size_t)row * 128 + col] = acc[mt][nt][rg];
      }
    }
}

// ---------------- bf16x3 MFMA genA GEMM (split-K) ----------------
template <int AMODE>
__global__ __launch_bounds__(256) void k_mfma_genA(
    const float* __restrict__ P, const float* __restrict__ mv,
    const float* __restrict__ col1, const float* __restrict__ col2,
    const unsigned short* __restrict__ Bthi, const unsigned short* __restrict__ Btlo,
    float* __restrict__ partial, int KC) {
  __shared__ __align__(16) unsigned short sAh[128 * PAD];
  __shared__ __align__(16) unsigned short sAl[128 * PAD];
  __shared__ __align__(16) unsigned short sBh[128 * PAD];
  __shared__ __align__(16) unsigned short sBl[128 * PAD];
  int tid = threadIdx.x;
  int bm = blockIdx.y * 128;
  int k0 = blockIdx.z * KC;
  int lane = tid & 63, w = tid >> 6;
  int wm = (w & 1) * 64, wn = (w >> 1) * 64;
  int l15 = lane & 15, quad = lane >> 4;
  f32x4 zero = {0.f, 0.f, 0.f, 0.f};
  f32x4 acc[4][4];
#pragma unroll
  for (int mt = 0; mt < 4; mt++)
#pragma unroll
    for (int nt = 0; nt < 4; nt++) acc[mt][nt] = zero;

  for (int kt = 0; kt < KC; kt += 32) {
    int kr = tid >> 3;
    int mc = (tid & 7) * 16;
    int k = k0 + kt + kr;
    float mvk = (AMODE == 1) ? mv[k] : 0.f;
#pragma unroll
    for (int q = 0; q < 4; q++) {
      int m0 = mc + q * 4;
      float4 pv = *(const float4*)&P[(size_t)k * C + bm + m0];
      float4 c1 = *(const float4*)&col1[bm + m0];
      float wv[4];
      if (AMODE == 1) {
        wv[0] = pv.x * mvk / (c1.x * pv.x + 1.f);
        wv[1] = pv.y * mvk / (c1.y * pv.y + 1.f);
        wv[2] = pv.z * mvk / (c1.z * pv.z + 1.f);
        wv[3] = pv.w * mvk / (c1.w * pv.w + 1.f);
      } else {
        float4 c2 = *(const float4*)&col2[bm + m0];
        wv[0] = __expf(pv.x - c1.x) / c2.x;
        wv[1] = __expf(pv.y - c1.y) / c2.y;
        wv[2] = __expf(pv.z - c1.z) / c2.z;
        wv[3] = __expf(pv.w - c1.w) / c2.w;
      }
#pragma unroll
      for (int j = 0; j < 4; j++) {
        unsigned short hh = f2bf(wv[j]);
        sAh[(m0 + j) * PAD + kr] = hh;
        sAl[(m0 + j) * PAD + kr] = f2bf(wv[j] - bf2f(hh));
      }
    }
#pragma unroll
    for (int q = 0; q < 2; q++) {
      int f = q * 256 + tid;
      int row = f >> 2, ch = f & 3;
      size_t gb = (size_t)row * N + k0 + kt + ch * 8;
      int ls = row * PAD + ch * 8;
      *(uint4*)&sBh[ls] = *(const uint4*)&Bthi[gb];
      *(uint4*)&sBl[ls] = *(const uint4*)&Btlo[gb];
    }
    __syncthreads();
    bf16x8 ah[4], al[4], bh[4], bl[4];
#pragma unroll
    for (int t = 0; t < 4; t++) {
      int ar = (wm + t * 16 + l15) * PAD + quad * 8;
      ah[t] = *(const bf16x8*)&sAh[ar];
      al[t] = *(const bf16x8*)&sAl[ar];
      int br = (wn + t * 16 + l15) * PAD + quad * 8;
      bh[t] = *(const bf16x8*)&sBh[br];
      bl[t] = *(const bf16x8*)&sBl[br];
    }
#pragma unroll
    for (int mt = 0; mt < 4; mt++)
#pragma unroll
      for (int nt = 0; nt < 4; nt++) {
        acc[mt][nt] = __builtin_amdgcn_mfma_f32_16x16x32_bf16(ah[mt], bh[nt], acc[mt][nt], 0, 0, 0);
        acc[mt][nt] = __builtin_amdgcn_mfma_f32_16x16x32_bf16(ah[mt], bl[nt], acc[mt][nt], 0, 0, 0);
        acc[mt][nt] = __builtin_amdgcn_mfma_f32_16x16x32_bf16(al[mt], bh[nt], acc[mt][nt], 0, 0, 0);
      }
    __syncthreads();
  }
  float* pp = partial + (size_t)blockIdx.z * C * 128;
#pragma unroll
  for (int mt = 0; mt < 4; mt++)
#pragma unroll
    for (int nt = 0; nt < 4; nt++) {
      int col = wn + nt * 16 + l15;
#pragma unroll
      for (int rg = 0; rg < 4; rg++) {
        int row = bm + wm + mt * 16 + quad * 4 + rg;
        pp[(size_t)row * 128 + col] = acc[mt][nt][rg];
      }
    }
}

// ---------------- bf16x3 MFMA linear, 32-row blocks ----------------
template <int EPI>
__global__ __launch_bounds__(256) void k_mfma_lin(
    const float* __restrict__ A, const float* __restrict__ Wt,
    const float* __restrict__ bias, const float* __restrict__ aux,
    float* __restrict__ out) {
  __shared__ __align__(16) unsigned short sAh[32 * PAD];
  __shared__ __align__(16) unsigned short sAl[32 * PAD];
  __shared__ __align__(16) unsigned short sWh[128 * PAD];
  __shared__ __align__(16) unsigned short sWl[128 * PAD];
  int tid = threadIdx.x;
  int bm = blockIdx.y * 32;
  int lane = tid & 63, w = tid >> 6;
  int rt = (w & 1) * 16, ch2 = (w >> 1) * 64;
  int l15 = lane & 15, quad = lane >> 4;
  f32x4 zero = {0.f, 0.f, 0.f, 0.f};
  f32x4 acc[4];
#pragma unroll
  for (int nt = 0; nt < 4; nt++) acc[nt] = zero;

  for (int kt = 0; kt < 128; kt += 32) {
    {
      int arow = tid >> 3, ach = tid & 7;
      float4 av = *(const float4*)&A[(size_t)(bm + arow) * 128 + kt + ach * 4];
      float aa[4] = {av.x, av.y, av.z, av.w};
      int ls = arow * PAD + ach * 4;
#pragma unroll
      for (int c = 0; c < 4; c++) {
        unsigned short hh = f2bf(aa[c]);
        sAh[ls + c] = hh;
        sAl[ls + c] = f2bf(aa[c] - bf2f(hh));
      }
    }
#pragma unroll
    for (int q = 0; q < 4; q++) {
      int f = q * 256 + tid;
      int wrow = f >> 3, wch = f & 7;
      float4 wv = *(const float4*)&Wt[(size_t)wrow * 128 + kt + wch * 4];
      float ww[4] = {wv.x, wv.y, wv.z, wv.w};
      int ls = wrow * PAD + wch * 4;
#pragma unroll
      for (int c = 0; c < 4; c++) {
        unsigned short hh = f2bf(ww[c]);
        sWh[ls + c] = hh;
        sWl[ls + c] = f2bf(ww[c] - bf2f(hh));
      }
    }
    __syncthreads();
    bf16x8 ah, al, bh[4], bl[4];
    {
      int ar = (rt + l15) * PAD + quad * 8;
      ah = *(const bf16x8*)&sAh[ar];
      al = *(const bf16x8*)&sAl[ar];
    }
#pragma unroll
    for (int nt = 0; nt < 4; nt++) {
      int br = (ch2 + nt * 16 + l15) * PAD + quad * 8;
      bh[nt] = *(const bf16x8*)&sWh[br];
      bl[nt] = *(const bf16x8*)&sWl[br];
    }
#pragma unroll
    for (int nt = 0; nt < 4; nt++) {
      acc[nt] = __builtin_amdgcn_mfma_f32_16x16x32_bf16(ah, bh[nt], acc[nt], 0, 0, 0);
      acc[nt] = __builtin_amdgcn_mfma_f32_16x16x32_bf16(ah, bl[nt], acc[nt], 0, 0, 0);
      acc[nt] = __builtin_amdgcn_mfma_f32_16x16x32_bf16(al, bh[nt], acc[nt], 0, 0, 0);
    }
    __syncthreads();
  }
#pragma unroll
  for (int nt = 0; nt < 4; nt++) {
    int col = ch2 + nt * 16 + l15;
    float bv = bias[col];
#pragma unroll
    for (int rg = 0; rg < 4; rg++) {
      int row = bm + rt + quad * 4 + rg;
      size_t off = (size_t)row * 128 + col;
      float v = acc[nt][rg] + bv;
      if (EPI == 0) out[off] = v;
      else if (EPI == 1) out[off] = lrelu(v);
      else if (EPI == 2) out[off] += lrelu(v);
      else out[off] = aux[off] - v;
    }
  }
}

__global__ __launch_bounds__(256) void k_scatter(
    const float* __restrict__ mtv, const int* __restrict__ mtj,
    const float* __restrict__ h, float* __restrict__ hidden2,
    float* __restrict__ colsum_m) {
  int i = blockIdx.x * 4 + (threadIdx.x >> 6);
  int lane = threadIdx.x & 63;
  float h0 = h[(size_t)i * H + lane], h1 = h[(size_t)i * H + 64 + lane];
#pragma unroll
  for (int s = 0; s < 3; s++) {
    float v = mtv[i * 3 + s];
    int j = mtj[i * 3 + s];
    atomicAdd(&hidden2[(size_t)j * H + lane], v * h0);
    atomicAdd(&hidden2[(size_t)j * H + 64 + lane], v * h1);
    if (lane == s) atomicAdd(&colsum_m[j], v);
  }
}

// reduce split-K partials; optional per-row scale (mul) or divisor (div);
// optional bf16 hi/lo pair emission
__global__ __launch_bounds__(256) void k_reduce(
    const float* __restrict__ partial, float* __restrict__ out, int cnt,
    size_t slot, size_t size4, const float* __restrict__ scalem,
    const float* __restrict__ divm, unsigned short* __restrict__ hi,
    unsigned short* __restrict__ lo) {
  size_t idx = (size_t)blockIdx.x * 256 + threadIdx.x;
  if (idx >= size4) return;
  float4 s = {0, 0, 0, 0};
  for (int c = 0; c < cnt; c++) {
    float4 v = *(const float4*)&partial[c * slot + idx * 4];
    s.x += v.x; s.y += v.y; s.z += v.z; s.w += v.w;
  }
  if (scalem) {
    float sc = scalem[idx >> 5];
    s.x *= sc; s.y *= sc; s.z *= sc; s.w *= sc;
  }
  if (divm) {
    float sc = 1.f / divm[idx >> 5];
    s.x *= sc; s.y *= sc; s.z *= sc; s.w *= sc;
  }
  *(float4*)&out[idx * 4] = s;
  if (hi) {
    float vv[4] = {s.x, s.y, s.z, s.w};
    unsigned short h[4], l[4];
#pragma unroll
    for (int c = 0; c < 4; c++) {
      h[c] = f2bf(vv[c]);
      l[c] = f2bf(vv[c] - bf2f(h[c]));
    }
    uint2 ph = {(unsigned)h[0] | ((unsigned)h[1] << 16),
                (unsigned)h[2] | ((unsigned)h[3] << 16)};
    uint2 pl = {(unsigned)l[0] | ((unsigned)l[1] << 16),
                (unsigned)l[2] | ((unsigned)l[3] << 16)};
    *(uint2*)&hi[idx * 4] = ph;
    *(uint2*)&lo[idx * 4] = pl;
  }
}

// ---------------- launch ----------------

extern "C" void kernel_launch(void* const* d_in, const int* in_sizes, int n_in,
                              void* d_out, int out_size, void* d_ws, size_t ws_size,
                              hipStream_t stream) {
  (void)in_sizes; (void)n_in; (void)out_size;
  const float* x   = (const float*)d_in[0];
  const float* cm  = (const float*)d_in[1];
  const float* mv  = (const float*)d_in[2];
  const float* W_ps = (const float*)d_in[3],  *b_ps = (const float*)d_in[4];
  const float* W_psf = (const float*)d_in[5], *b_psf = (const float*)d_in[6];
  const float* W_psb = (const float*)d_in[7], *b_psb = (const float*)d_in[8];
  const float* W_hs = (const float*)d_in[9],  *b_hs = (const float*)d_in[10];
  const float* W_hsf = (const float*)d_in[11], *b_hsf = (const float*)d_in[12];
  const float* W_hsb = (const float*)d_in[13], *b_hsb = (const float*)d_in[14];
  const float* W_in = (const float*)d_in[15], *b_in = (const float*)d_in[16];
  const float* W_out = (const float*)d_in[17], *b_out = (const float*)d_in[18];
  float* out = (float*)d_out;

  float* W = (float*)d_ws;
  size_t o = 0;
  auto alloc = [&](size_t n) { float* p = W + o; o += n; return p; };
  float* colsum_c = alloc(C);
  float* colmax   = alloc(C);
  float* colsumexp= alloc(C);
  float* valid1   = alloc(C);
  float* hnorm_ps = alloc(C);
  float* xnorm    = alloc(N);
  float* diagv    = alloc(N);
  float* colsum_m = alloc(N);
  float* valid2f  = alloc(N);
  float* lsum     = alloc(N);
  float* mtv      = alloc(3 * N);
  int*   mtj      = (int*)alloc(3 * N);
  float* hidden1  = alloc((size_t)C * H);
  float* hidden_ps= alloc((size_t)C * H);
  float* scores   = alloc((size_t)N * C);
  float* ps_pre   = alloc((size_t)N * H);   // later hs_pre
  float* p_shared = alloc((size_t)N * H);   // later h_shared
  float* all_info = alloc((size_t)N * H);
  float* hbuf     = alloc((size_t)N * H);   // h; later indiv (in-place)
  float* hhat     = alloc((size_t)N * H);
  float* hidden2  = alloc((size_t)N * H);
  float* candv    = alloc((size_t)64 * 4 * N);  // 4 MB
  int*   candi    = (int*)alloc((size_t)64 * 4 * N);
  unsigned short* xhi    = (unsigned short*)alloc((size_t)N * H / 2);
  unsigned short* xlo    = (unsigned short*)alloc((size_t)N * H / 2);
  unsigned short* hhathi = (unsigned short*)alloc((size_t)N * H / 2);
  unsigned short* hhatlo = (unsigned short*)alloc((size_t)N * H / 2);
  unsigned short* h2hi   = (unsigned short*)alloc((size_t)N * H / 2);
  unsigned short* h2lo   = (unsigned short*)alloc((size_t)N * H / 2);
  unsigned short* h1hi   = (unsigned short*)alloc((size_t)C * H / 2);
  unsigned short* h1lo   = (unsigned short*)alloc((size_t)C * H / 2);
  unsigned short* hpshi  = (unsigned short*)alloc((size_t)C * H / 2);
  unsigned short* hpslo  = (unsigned short*)alloc((size_t)C * H / 2);
  unsigned short* cshi   = (unsigned short*)alloc((size_t)N * C / 2);
  unsigned short* cslo   = (unsigned short*)alloc((size_t)N * C / 2);
  unsigned short* hpst_hi= (unsigned short*)alloc((size_t)H * C / 2);
  unsigned short* hpst_lo= (unsigned short*)alloc((size_t)H * C / 2);
  unsigned short* h2t_hi = (unsigned short*)alloc((size_t)H * N / 2);
  unsigned short* h2t_lo = (unsigned short*)alloc((size_t)H * N / 2);
  unsigned short* xt_hi  = (unsigned short*)alloc((size_t)H * N / 2);
  unsigned short* xt_lo  = (unsigned short*)alloc((size_t)H * N / 2);
  float* Ebuf     = alloc((size_t)N * N / 2);   // 32 MB: E as single bf16
  unsigned short* Ehi = (unsigned short*)Ebuf;
  float* partial  = W + o;
  size_t rem = ws_size / 4 - o;
  int Z = (rem >= (size_t)16 * N * H) ? 16 : 8;
  int KC = 4096 / Z;

  hipMemsetAsync(colsum_c, 0, C * sizeof(float), stream);
  hipMemsetAsync(colsum_m, 0, N * sizeof(float), stream);
  hipMemsetAsync(lsum, 0, N * sizeof(float), stream);
  hipMemsetAsync(hidden2, 0, (size_t)N * H * sizeof(float), stream);

  dim3 blk(256);
  // --- ps branch ---
  k_split<<<dim3(N * H / 1024), blk, 0, stream>>>(x, xhi, xlo);
  k_tsplit<<<dim3(N / 32), blk, 0, stream>>>(x, xt_hi, xt_lo, N);
  k_colsum_s2c<<<dim3(C / 64, 16), dim3(64), 0, stream>>>(cm, mv, colsum_c);
  k_mfma_genA<1><<<dim3(1, C / 128, 32), blk, 0, stream>>>(
      cm, mv, colsum_c, nullptr, xt_hi, xt_lo, partial, N / 32);
  k_reduce<<<dim3(C * H / 4 / 256), blk, 0, stream>>>(
      partial, hidden1, 32, (size_t)C * H, (size_t)C * H / 4, nullptr, nullptr,
      h1hi, h1lo);
  k_valid1<<<dim3(C), dim3(64), 0, stream>>>(hidden1, valid1);
  k_mfma_nt<0><<<dim3(C / 128, N / 128), blk, 0, stream>>>(
      xhi, xlo, h1hi, h1lo, nullptr, scores, nullptr, nullptr, C);
  k_colstats<<<dim3(C), blk, 0, stream>>>(scores, colmax, colsumexp);
  k_mfma_genA<2><<<dim3(1, C / 128, 32), blk, 0, stream>>>(
      scores, nullptr, colmax, colsumexp, xt_hi, xt_lo, partial, N / 32);
  k_reduce<<<dim3(C * H / 4 / 256), blk, 0, stream>>>(
      partial, hidden_ps, 32, (size_t)C * H, (size_t)C * H / 4, valid1, nullptr,
      hpshi, hpslo);
  k_rownorm128<<<dim3(N), dim3(64), 0, stream>>>(x, xnorm);
  k_rownorm128<<<dim3(C), dim3(64), 0, stream>>>(hidden_ps, hnorm_ps);
  k_mfma_nt<0><<<dim3(C / 128, N / 128), blk, 0, stream>>>(
      xhi, xlo, hpshi, hpslo, nullptr, scores, nullptr, nullptr, C);
  k_cs_softmax<<<dim3(N), blk, 0, stream>>>(scores, xnorm, hnorm_ps, valid1,
                                            cshi, cslo);
  k_tsplit<<<dim3(C / 32), blk, 0, stream>>>(hidden_ps, hpst_hi, hpst_lo, C);
  k_mfma_kn<1><<<dim3(1, N / 128, 4), blk, 0, stream>>>(
      cshi, cslo, hpst_hi, hpst_lo, partial, C, C / 4);
  k_reduce<<<dim3(N * H / 4 / 256), blk, 0, stream>>>(
      partial, ps_pre, 4, (size_t)N * H, (size_t)N * H / 4, nullptr, nullptr,
      nullptr, nullptr);
  k_mfma_lin<0><<<dim3(1, N / 32), blk, 0, stream>>>(
      ps_pre, W_ps, b_ps, nullptr, p_shared);
  k_mfma_lin<3><<<dim3(1, N / 32), blk, 0, stream>>>(
      p_shared, W_psb, b_psb, x, hbuf);                      // h = x - p_back
  k_mfma_lin<1><<<dim3(1, N / 32), blk, 0, stream>>>(
      p_shared, W_psf, b_psf, nullptr, all_info);            // out_ps
  // --- hs branch ---
  k_hhat<<<dim3(N), dim3(64), 0, stream>>>(hbuf, hhat, hhathi, hhatlo, diagv);
  k_mfma_top<<<dim3(N / 128, N / 128), blk, 0, stream>>>(hhathi, hhatlo,
                                                         candv, candi);
  k_merge4<<<dim3(N / 4), blk, 0, stream>>>(candv, candi, hhat, mtv, mtj);
  k_scatter<<<dim3(N / 4), blk, 0, stream>>>(mtv, mtj, hbuf, hidden2, colsum_m);
  k_fin_hidden2<<<dim3(N), dim3(64), 0, stream>>>(hbuf, diagv, colsum_m, hidden2,
                                                  h2hi, h2lo, valid2f);
  k_mfma_nt<3><<<dim3(N / 128, N / 128), blk, 0, stream>>>(
      hhathi, hhatlo, h2hi, h2lo, valid2f, nullptr, Ehi, lsum, N);
  k_tsplit<<<dim3(N / 32), blk, 0, stream>>>(hidden2, h2t_hi, h2t_lo, N);
  k_mfma_kn<0><<<dim3(1, N / 128, Z), blk, 0, stream>>>(
      Ehi, nullptr, h2t_hi, h2t_lo, partial, N, KC);
  k_reduce<<<dim3(N * H / 4 / 256), blk, 0, stream>>>(
      partial, ps_pre, Z, (size_t)N * H, (size_t)N * H / 4, nullptr, lsum,
      nullptr, nullptr);  // hs_pre = U / l
  k_mfma_lin<0><<<dim3(1, N / 32), blk, 0, stream>>>(
      ps_pre, W_hs, b_hs, nullptr, p_shared);                // h_shared
  k_mfma_lin<2><<<dim3(1, N / 32), blk, 0, stream>>>(
      p_shared, W_hsf, b_hsf, nullptr, all_info);            // += out_hs
  k_mfma_lin<3><<<dim3(1, N / 32), blk, 0, stream>>>(
      p_shared, W_hsb, b_hsb, hbuf, hbuf);                   // indiv = h - h_back
  k_mfma_lin<2><<<dim3(1, N / 32), blk, 0, stream>>>(
      hbuf, W_in, b_in, nullptr, all_info);                  // += out_indi
  k_final<<<dim3(N), dim3(64), 0, stream>>>(all_info, W_out, b_out, out);
}

// Round 10
// 414.287 us; speedup vs baseline: 1.1717x; 1.1717x over previous
//
#include <hip/hip_runtime.h>
#include <hip/hip_fp16.h>
#include <math.h>

#define N 4096
#define C 512
#define H 128
#define PAD 40  // ushort row pitch for MFMA LDS tiles (80 B: 16B-aligned, 2-way banks)

typedef __attribute__((ext_vector_type(8))) short bf16x8;
typedef __attribute__((ext_vector_type(4))) float f32x4;

// ---------------- helpers ----------------

__device__ inline float wave_reduce_sum(float v) {
#pragma unroll
  for (int m = 32; m; m >>= 1) v += __shfl_xor(v, m);
  return v;
}

__device__ inline float lrelu(float v) { return v > 0.f ? v : 0.01f * v; }

__device__ inline bool better(float v, int j, float w, int k) {
  return (v > w) || (v == w && j < k);
}

__device__ inline void top3_ins(float v, int j, float& v0, int& j0,
                                float& v1, int& j1, float& v2, int& j2) {
  if (better(v, j, v0, j0)) { v2 = v1; j2 = j1; v1 = v0; j1 = j0; v0 = v; j0 = j; }
  else if (better(v, j, v1, j1)) { v2 = v1; j2 = j1; v1 = v; j1 = j; }
  else if (better(v, j, v2, j2)) { v2 = v; j2 = j; }
}

__device__ inline void ins5(float s, int j, float v[5], int jx[5]) {
  if (!better(s, j, v[4], jx[4])) return;
  if (better(s, j, v[0], jx[0])) {
    v[4]=v[3]; jx[4]=jx[3]; v[3]=v[2]; jx[3]=jx[2]; v[2]=v[1]; jx[2]=jx[1];
    v[1]=v[0]; jx[1]=jx[0]; v[0]=s; jx[0]=j;
  } else if (better(s, j, v[1], jx[1])) {
    v[4]=v[3]; jx[4]=jx[3]; v[3]=v[2]; jx[3]=jx[2]; v[2]=v[1]; jx[2]=jx[1];
    v[1]=s; jx[1]=j;
  } else if (better(s, j, v[2], jx[2])) {
    v[4]=v[3]; jx[4]=jx[3]; v[3]=v[2]; jx[3]=jx[2]; v[2]=s; jx[2]=j;
  } else if (better(s, j, v[3], jx[3])) {
    v[4]=v[3]; jx[4]=jx[3]; v[3]=s; jx[3]=j;
  } else {
    v[4]=s; jx[4]=j;
  }
}

__device__ inline unsigned short f2bf(float f) {
  unsigned u = __float_as_uint(f);
  unsigned r = u + 0x7fffu + ((u >> 16) & 1u);
  return (unsigned short)(r >> 16);
}
__device__ inline float bf2f(unsigned short h) {
  return __uint_as_float(((unsigned)h) << 16);
}

// ---------------- split fp32 -> bf16 hi/lo ----------------
__global__ __launch_bounds__(256) void k_split(const float* __restrict__ in,
                                               unsigned short* __restrict__ hi,
                                               unsigned short* __restrict__ lo) {
  int idx = (blockIdx.x * 256 + threadIdx.x) * 4;
  float4 v = *(const float4*)&in[idx];
  float vv[4] = {v.x, v.y, v.z, v.w};
  unsigned short h[4], l[4];
#pragma unroll
  for (int c = 0; c < 4; c++) {
    h[c] = f2bf(vv[c]);
    l[c] = f2bf(vv[c] - bf2f(h[c]));
  }
  uint2 ph = {(unsigned)h[0] | ((unsigned)h[1] << 16),
              (unsigned)h[2] | ((unsigned)h[3] << 16)};
  uint2 pl = {(unsigned)l[0] | ((unsigned)l[1] << 16),
              (unsigned)l[2] | ((unsigned)l[3] << 16)};
  *(uint2*)&hi[idx] = ph;
  *(uint2*)&lo[idx] = pl;
}

// transpose + split: in [R,128] fp32 -> thi/tlo [128,R] ushort
__global__ __launch_bounds__(256) void k_tsplit(const float* __restrict__ in,
                                                unsigned short* __restrict__ thi,
                                                unsigned short* __restrict__ tlo,
                                                int R) {
  __shared__ float tile[32][132];
  int r0 = blockIdx.x * 32, tid = threadIdx.x;
#pragma unroll
  for (int q = 0; q < 4; q++) {
    int f = q * 256 + tid;
    int row = f >> 5, ch = f & 31;
    *(float4*)&tile[row][ch * 4] = *(const float4*)&in[(size_t)(r0 + row) * 128 + ch * 4];
  }
  __syncthreads();
  int c = tid & 127, half = tid >> 7;
  unsigned short hh[16], ll[16];
#pragma unroll
  for (int rr = 0; rr < 16; rr++) {
    float v = tile[half * 16 + rr][c];
    hh[rr] = f2bf(v);
    ll[rr] = f2bf(v - bf2f(hh[rr]));
  }
  size_t off = (size_t)c * R + r0 + half * 16;
  uint4 ph0 = {(unsigned)hh[0] | ((unsigned)hh[1] << 16), (unsigned)hh[2] | ((unsigned)hh[3] << 16),
               (unsigned)hh[4] | ((unsigned)hh[5] << 16), (unsigned)hh[6] | ((unsigned)hh[7] << 16)};
  uint4 ph1 = {(unsigned)hh[8] | ((unsigned)hh[9] << 16), (unsigned)hh[10] | ((unsigned)hh[11] << 16),
               (unsigned)hh[12] | ((unsigned)hh[13] << 16), (unsigned)hh[14] | ((unsigned)hh[15] << 16)};
  uint4 pl0 = {(unsigned)ll[0] | ((unsigned)ll[1] << 16), (unsigned)ll[2] | ((unsigned)ll[3] << 16),
               (unsigned)ll[4] | ((unsigned)ll[5] << 16), (unsigned)ll[6] | ((unsigned)ll[7] << 16)};
  uint4 pl1 = {(unsigned)ll[8] | ((unsigned)ll[9] << 16), (unsigned)ll[10] | ((unsigned)ll[11] << 16),
               (unsigned)ll[12] | ((unsigned)ll[13] << 16), (unsigned)ll[14] | ((unsigned)ll[15] << 16)};
  *(uint4*)&thi[off] = ph0; *(uint4*)&thi[off + 8] = ph1;
  *(uint4*)&tlo[off] = pl0; *(uint4*)&tlo[off + 8] = pl1;
}

// ---------------- small kernels ----------------

__global__ __launch_bounds__(64) void k_colsum_s2c(
    const float* __restrict__ cm, const float* __restrict__ mv,
    float* __restrict__ colsum_c) {
  int c = blockIdx.x * 64 + threadIdx.x;
  int i0 = blockIdx.y * 256;
  float acc = 0.f;
  for (int i = i0; i < i0 + 256; i++) acc += cm[(size_t)i * C + c] * mv[i];
  atomicAdd(&colsum_c[c], acc);
}

__global__ __launch_bounds__(64) void k_valid1(const float* __restrict__ hid,
                                               float* __restrict__ valid1) {
  int c = blockIdx.x, t = threadIdx.x;
  float s = hid[(size_t)c * H + t] + hid[(size_t)c * H + 64 + t];
  s = wave_reduce_sum(s);
  if (t == 0) valid1[c] = (s != 0.f) ? 1.f : 0.f;
}

__global__ __launch_bounds__(64) void k_rownorm128(const float* __restrict__ A,
                                                   float* __restrict__ nrm) {
  int r = blockIdx.x, t = threadIdx.x;
  float a = A[(size_t)r * H + t], b = A[(size_t)r * H + 64 + t];
  float ss = wave_reduce_sum(a * a + b * b);
  if (t == 0) nrm[r] = sqrtf(ss);
}

__global__ __launch_bounds__(256) void k_colstats(const float* __restrict__ sc,
                                                  float* __restrict__ colmax,
                                                  float* __restrict__ colsum) {
  __shared__ float red[256];
  int c = blockIdx.x, t = threadIdx.x;
  float v[16];
  float m = -3e38f;
#pragma unroll
  for (int q = 0; q < 16; q++) {
    v[q] = sc[(size_t)(q * 256 + t) * C + c];
    m = fmaxf(m, v[q]);
  }
  red[t] = m; __syncthreads();
  for (int s = 128; s; s >>= 1) { if (t < s) red[t] = fmaxf(red[t], red[t + s]); __syncthreads(); }
  m = red[0]; __syncthreads();
  float sum = 0.f;
#pragma unroll
  for (int q = 0; q < 16; q++) sum += __expf(v[q] - m);
  red[t] = sum; __syncthreads();
  for (int s = 128; s; s >>= 1) { if (t < s) red[t] += red[t + s]; __syncthreads(); }
  if (t == 0) { colmax[c] = m; colsum[c] = red[0]; }
}

// row softmax of cos-sim -> bf16 hi/lo pairs
__global__ __launch_bounds__(256) void k_cs_softmax(
    const float* __restrict__ sc, const float* __restrict__ xnorm,
    const float* __restrict__ hnorm, const float* __restrict__ valid1,
    unsigned short* __restrict__ cshi, unsigned short* __restrict__ cslo) {
  __shared__ float red[256];
  int i = blockIdx.x, t = threadIdx.x;
  float xn = xnorm[i];
  float r0 = sc[(size_t)i * C + t], r1 = sc[(size_t)i * C + 256 + t];
  float d0 = xn * hnorm[t], d1 = xn * hnorm[256 + t];
  float c0 = r0 / (d0 == 0.f ? 1.f : d0);
  float c1 = r1 / (d1 == 0.f ? 1.f : d1);
  float s0 = (valid1[t] != 0.f) ? c0 : -3e38f;
  float s1 = (valid1[256 + t] != 0.f) ? c1 : -3e38f;
  red[t] = fmaxf(s0, s1); __syncthreads();
  for (int s = 128; s; s >>= 1) { if (t < s) red[t] = fmaxf(red[t], red[t + s]); __syncthreads(); }
  float m = red[0]; __syncthreads();
  float p0 = (s0 > -1e37f) ? __expf(s0 - m) : 0.f;
  float p1 = (s1 > -1e37f) ? __expf(s1 - m) : 0.f;
  red[t] = p0 + p1; __syncthreads();
  for (int s = 128; s; s >>= 1) { if (t < s) red[t] += red[t + s]; __syncthreads(); }
  float inv = 1.f / red[0];
  float a = p0 * inv, b = p1 * inv;
  unsigned short ha = f2bf(a), hb = f2bf(b);
  cshi[(size_t)i * C + t] = ha;
  cslo[(size_t)i * C + t] = f2bf(a - bf2f(ha));
  cshi[(size_t)i * C + 256 + t] = hb;
  cslo[(size_t)i * C + 256 + t] = f2bf(b - bf2f(hb));
}

// hhat + pairs + diag value
__global__ __launch_bounds__(64) void k_hhat(const float* __restrict__ h,
                                             float* __restrict__ hhat,
                                             unsigned short* __restrict__ hhi,
                                             unsigned short* __restrict__ hlo,
                                             float* __restrict__ diagv) {
  int i = blockIdx.x, t = threadIdx.x;
  float a = h[(size_t)i * H + t], b = h[(size_t)i * H + 64 + t];
  float ss = wave_reduce_sum(a * a + b * b);
  float hn = sqrtf(ss);
  float den = hn * hn;
  float dg = (den == 0.f) ? 0.f : ss / den;
  float inv = (ss > 0.f) ? (1.f / hn) : 1.f;
  float va = a * inv, vb = b * inv;
  hhat[(size_t)i * H + t] = va;
  hhat[(size_t)i * H + 64 + t] = vb;
  unsigned short ha = f2bf(va), hb = f2bf(vb);
  hhi[(size_t)i * H + t] = ha;
  hlo[(size_t)i * H + t] = f2bf(va - bf2f(ha));
  hhi[(size_t)i * H + 64 + t] = hb;
  hlo[(size_t)i * H + 64 + t] = f2bf(vb - bf2f(hb));
  if (t == 0) diagv[i] = dg;
}

// finalize hidden2 + h2hat pairs + valid2f
__global__ __launch_bounds__(64) void k_fin_hidden2(
    const float* __restrict__ h, const float* __restrict__ diagv,
    const float* __restrict__ colsum_m, float* __restrict__ hidden2,
    unsigned short* __restrict__ h2hi, unsigned short* __restrict__ h2lo,
    float* __restrict__ valid2f) {
  int j = blockIdx.x, t = threadIdx.x;
  float add = (colsum_m[j] != 0.f) ? diagv[j] : 0.f;
  float a = hidden2[(size_t)j * H + t] + add * h[(size_t)j * H + t];
  float b = hidden2[(size_t)j * H + 64 + t] + add * h[(size_t)j * H + 64 + t];
  float s = a + b, ss = a * a + b * b;
#pragma unroll
  for (int m = 32; m; m >>= 1) { s += __shfl_xor(s, m); ss += __shfl_xor(ss, m); }
  bool valid = (s != 0.f);
  a = valid ? a : 0.f; b = valid ? b : 0.f;
  hidden2[(size_t)j * H + t] = a;
  hidden2[(size_t)j * H + 64 + t] = b;
  float inv = (valid && ss > 0.f) ? (1.f / sqrtf(ss)) : 1.f;
  float va = a * inv, vb = b * inv;
  unsigned short ha = f2bf(va), hb = f2bf(vb);
  h2hi[(size_t)j * H + t] = ha;
  h2lo[(size_t)j * H + t] = f2bf(va - bf2f(ha));
  h2hi[(size_t)j * H + 64 + t] = hb;
  h2lo[(size_t)j * H + 64 + t] = f2bf(vb - bf2f(hb));
  if (t == 0) valid2f[j] = valid ? 1.f : 0.f;
}

__global__ __launch_bounds__(64) void k_final(const float* __restrict__ ai,
                                              const float* __restrict__ Wout,
                                              const float* __restrict__ bout,
                                              float* __restrict__ out) {
  int i = blockIdx.x, t = threadIdx.x;
  float s = ai[(size_t)i * H + t] * Wout[t] + ai[(size_t)i * H + 64 + t] * Wout[64 + t];
  s = wave_reduce_sum(s);
  if (t == 0) out[i] = s + bout[0];
}

// ---------------- bf16x3 MFMA NT GEMM: A[M,128] @ B[Nn,128]^T ----------------
// EPI 0: fp32 store; 2: diag-zeroed fp16 store into ehi;
// 3: E=exp(s-1) masked -> single bf16 (ehi) + row-sum atomics into lsum
template <int EPI>
__global__ __launch_bounds__(256) void k_mfma_nt(
    const unsigned short* __restrict__ Ahi, const unsigned short* __restrict__ Alo,
    const unsigned short* __restrict__ Bhi, const unsigned short* __restrict__ Blo,
    const float* __restrict__ validn, float* __restrict__ out,
    unsigned short* __restrict__ ehi, float* __restrict__ lsum, int Nn) {
  __shared__ __align__(16) unsigned short sAh[128 * PAD];
  __shared__ __align__(16) unsigned short sAl[128 * PAD];
  __shared__ __align__(16) unsigned short sBh[128 * PAD];
  __shared__ __align__(16) unsigned short sBl[128 * PAD];
  int tid = threadIdx.x;
  int bm = blockIdx.y * 128, bn = blockIdx.x * 128;
  int lane = tid & 63, w = tid >> 6;
  int wm = (w & 1) * 64, wn = (w >> 1) * 64;
  int l15 = lane & 15, quad = lane >> 4;
  f32x4 zero = {0.f, 0.f, 0.f, 0.f};
  f32x4 acc[4][4];
#pragma unroll
  for (int mt = 0; mt < 4; mt++)
#pragma unroll
    for (int nt = 0; nt < 4; nt++) acc[mt][nt] = zero;

  for (int kt = 0; kt < 128; kt += 32) {
#pragma unroll
    for (int q = 0; q < 2; q++) {
      int f = tid * 2 + q;
      int row = f >> 2, ch = f & 3;
      size_t ga = (size_t)(bm + row) * 128 + kt + ch * 8;
      size_t gb = (size_t)(bn + row) * 128 + kt + ch * 8;
      int ls = row * PAD + ch * 8;
      *(uint4*)&sAh[ls] = *(const uint4*)&Ahi[ga];
      *(uint4*)&sAl[ls] = *(const uint4*)&Alo[ga];
      *(uint4*)&sBh[ls] = *(const uint4*)&Bhi[gb];
      *(uint4*)&sBl[ls] = *(const uint4*)&Blo[gb];
    }
    __syncthreads();
    bf16x8 ah[4], al[4], bh[4], bl[4];
#pragma unroll
    for (int t = 0; t < 4; t++) {
      int ar = (wm + t * 16 + l15) * PAD + quad * 8;
      ah[t] = *(const bf16x8*)&sAh[ar];
      al[t] = *(const bf16x8*)&sAl[ar];
      int br = (wn + t * 16 + l15) * PAD + quad * 8;
      bh[t] = *(const bf16x8*)&sBh[br];
      bl[t] = *(const bf16x8*)&sBl[br];
    }
#pragma unroll
    for (int mt = 0; mt < 4; mt++)
#pragma unroll
      for (int nt = 0; nt < 4; nt++) {
        acc[mt][nt] = __builtin_amdgcn_mfma_f32_16x16x32_bf16(ah[mt], bh[nt], acc[mt][nt], 0, 0, 0);
        acc[mt][nt] = __builtin_amdgcn_mfma_f32_16x16x32_bf16(ah[mt], bl[nt], acc[mt][nt], 0, 0, 0);
        acc[mt][nt] = __builtin_amdgcn_mfma_f32_16x16x32_bf16(al[mt], bh[nt], acc[mt][nt], 0, 0, 0);
      }
    __syncthreads();
  }
  if (EPI == 3) {
    float vm[4];
#pragma unroll
    for (int nt = 0; nt < 4; nt++) vm[nt] = validn[bn + wn + nt * 16 + l15];
#pragma unroll
    for (int mt = 0; mt < 4; mt++) {
#pragma unroll
      for (int rg = 0; rg < 4; rg++) {
        int row = bm + wm + mt * 16 + quad * 4 + rg;
        float rsum = 0.f;
#pragma unroll
        for (int nt = 0; nt < 4; nt++) {
          int col = bn + wn + nt * 16 + l15;
          float e = (vm[nt] != 0.f) ? __expf(acc[mt][nt][rg] - 1.f) : 0.f;
          rsum += e;
          ehi[(size_t)row * N + col] = f2bf(e);
        }
#pragma unroll
        for (int d = 1; d < 16; d <<= 1) rsum += __shfl_xor(rsum, d);
        if (l15 == 0) atomicAdd(&lsum[row], rsum);
      }
    }
  } else if (EPI == 2) {
#pragma unroll
    for (int mt = 0; mt < 4; mt++) {
#pragma unroll
      for (int nt = 0; nt < 4; nt++) {
        int col = bn + wn + nt * 16 + l15;
#pragma unroll
        for (int rg = 0; rg < 4; rg++) {
          int row = bm + wm + mt * 16 + quad * 4 + rg;
          float v = (row == col) ? 0.f : acc[mt][nt][rg];
          ehi[(size_t)row * N + col] = __half_as_ushort(__float2half(v));
        }
      }
    }
  } else {
#pragma unroll
    for (int mt = 0; mt < 4; mt++) {
#pragma unroll
      for (int nt = 0; nt < 4; nt++) {
        int col = bn + wn + nt * 16 + l15;
#pragma unroll
        for (int rg = 0; rg < 4; rg++) {
          int row = bm + wm + mt * 16 + quad * 4 + rg;
          out[(size_t)row * Nn + col] = acc[mt][nt][rg];
        }
      }
    }
  }
}

// ---------------- row top-k: approx top-5 from fp16 S, exact fp32 rescore -----
__global__ __launch_bounds__(256) void k_rowtop(
    const unsigned short* __restrict__ Sh, const float* __restrict__ hhat,
    float* __restrict__ mtv, int* __restrict__ mtj) {
  int i = blockIdx.x * 4 + (threadIdx.x >> 6);
  int lane = threadIdx.x & 63;
  const unsigned short* row = &Sh[(size_t)i * N];
  float v[5] = {-3e38f, -3e38f, -3e38f, -3e38f, -3e38f};
  int jx[5] = {0x7fffffff, 0x7fffffff, 0x7fffffff, 0x7fffffff, 0x7fffffff};
  for (int t = 0; t < 8; t++) {
    int base = t * 512 + lane * 8;
    uint4 p = *(const uint4*)&row[base];
    unsigned pk[4] = {p.x, p.y, p.z, p.w};
#pragma unroll
    for (int c = 0; c < 4; c++) {
      float e0 = __half2float(__ushort_as_half((unsigned short)(pk[c] & 0xffffu)));
      float e1 = __half2float(__ushort_as_half((unsigned short)(pk[c] >> 16)));
      ins5(e0, base + c * 2, v, jx);
      ins5(e1, base + c * 2 + 1, v, jx);
    }
  }
#pragma unroll
  for (int d = 1; d < 64; d <<= 1) {
    float fv[5]; int fj[5];
#pragma unroll
    for (int c = 0; c < 5; c++) { fv[c] = __shfl_xor(v[c], d); fj[c] = __shfl_xor(jx[c], d); }
#pragma unroll
    for (int c = 0; c < 5; c++) ins5(fv[c], fj[c], v, jx);
  }
  const float* hi = &hhat[(size_t)i * H];
  float b0 = -3e38f, b1 = -3e38f, b2 = -3e38f;
  int q0 = 0, q1 = 0, q2 = 0;
#pragma unroll
  for (int c = 0; c < 5; c++) {
    int j = jx[c];
    float s;
    if (j == i) {
      s = 0.f;
    } else {
      const float* hj = &hhat[(size_t)j * H];
      float p = hi[lane] * hj[lane] + hi[lane + 64] * hj[lane + 64];
      s = wave_reduce_sum(p);
    }
    top3_ins(s, j, b0, q0, b1, q1, b2, q2);
  }
  if (lane == 0) {
    mtv[i * 3 + 0] = b0; mtv[i * 3 + 1] = b1; mtv[i * 3 + 2] = b2;
    mtj[i * 3 + 0] = q0; mtj[i * 3 + 1] = q1; mtj[i * 3 + 2] = q2;
  }
}

// ---------------- bf16 MFMA KN GEMM (split-K): partial[z] = A @ B ------------
// ALO=1: A has hi/lo pairs (3 mfma); ALO=0: A single bf16 (2 mfma)
template <int ALO>
__global__ __launch_bounds__(256) void k_mfma_kn(
    const unsigned short* __restrict__ Ahi, const unsigned short* __restrict__ Alo,
    const unsigned short* __restrict__ Bthi, const unsigned short* __restrict__ Btlo,
    float* __restrict__ partial, int lda, int KC) {
  __shared__ __align__(16) unsigned short sAh[128 * PAD];
  __shared__ __align__(16) unsigned short sAl[128 * PAD];
  __shared__ __align__(16) unsigned short sBh[128 * PAD];
  __shared__ __align__(16) unsigned short sBl[128 * PAD];
  int tid = threadIdx.x;
  int bm = blockIdx.y * 128;
  int k0 = blockIdx.z * KC;
  int lane = tid & 63, w = tid >> 6;
  int wm = (w & 1) * 64, wn = (w >> 1) * 64;
  int l15 = lane & 15, quad = lane >> 4;
  f32x4 zero = {0.f, 0.f, 0.f, 0.f};
  f32x4 acc[4][4];
#pragma unroll
  for (int mt = 0; mt < 4; mt++)
#pragma unroll
    for (int nt = 0; nt < 4; nt++) acc[mt][nt] = zero;

  for (int kt = 0; kt < KC; kt += 32) {
#pragma unroll
    for (int q = 0; q < 2; q++) {
      int f = tid * 2 + q;
      int row = f >> 2, ch = f & 3;
      size_t ga = (size_t)(bm + row) * lda + k0 + kt + ch * 8;
      size_t gb = (size_t)row * lda + k0 + kt + ch * 8;
      int ls = row * PAD + ch * 8;
      *(uint4*)&sAh[ls] = *(const uint4*)&Ahi[ga];
      if (ALO) *(uint4*)&sAl[ls] = *(const uint4*)&Alo[ga];
      *(uint4*)&sBh[ls] = *(const uint4*)&Bthi[gb];
      *(uint4*)&sBl[ls] = *(const uint4*)&Btlo[gb];
    }
    __syncthreads();
    bf16x8 ah[4], al[4], bh[4], bl[4];
#pragma unroll
    for (int t = 0; t < 4; t++) {
      int ar = (wm + t * 16 + l15) * PAD + quad * 8;
      ah[t] = *(const bf16x8*)&sAh[ar];
      if (ALO) al[t] = *(const bf16x8*)&sAl[ar];
      int br = (wn + t * 16 + l15) * PAD + quad * 8;
      bh[t] = *(const bf16x8*)&sBh[br];
      bl[t] = *(const bf16x8*)&sBl[br];
    }
#pragma unroll
    for (int mt = 0; mt < 4; mt++)
#pragma unroll
      for (int nt = 0; nt < 4; nt++) {
        acc[mt][nt] = __builtin_amdgcn_mfma_f32_16x16x32_bf16(ah[mt], bh[nt], acc[mt][nt], 0, 0, 0);
        acc[mt][nt] = __builtin_amdgcn_mfma_f32_16x16x32_bf16(ah[mt], bl[nt], acc[mt][nt], 0, 0, 0);
        if (ALO)
          acc[mt][nt] = __builtin_amdgcn_mfma_f32_16x16x32_bf16(al[mt], bh[nt], acc[mt][nt], 0, 0, 0);
      }
    __syncthreads();
  }
  float* pp = partial + (size_t)blockIdx.z * N * 128;
#pragma unroll
  for (int mt = 0; mt < 4; mt++)
#pragma unroll
    for (int nt = 0; nt < 4; nt++) {
      int col = wn + nt * 16 + l15;
#pragma unroll
      for (int rg = 0; rg < 4; rg++) {
        int row = bm + wm + mt * 16 + quad * 4 + rg;
        pp[(size_t)row * 128 + col] = acc[mt][nt][rg];
      }
    }
}

// ---------------- bf16x3 MFMA genA GEMM (split-K) ----------------
template <int AMODE>
__global__ __launch_bounds__(256) void k_mfma_genA(
    const float* __restrict__ P, const float* __restrict__ mv,
    const float* __restrict__ col1, const float* __restrict__ col2,
    const unsigned short* __restrict__ Bthi, const unsigned short* __restrict__ Btlo,
    float* __restrict__ partial, int KC) {
  __shared__ __align__(16) unsigned short sAh[128 * PAD];
  __shared__ __align__(16) unsigned short sAl[128 * PAD];
  __shared__ __align__(16) unsigned short sBh[128 * PAD];
  __shared__ __align__(16) unsigned short sBl[128 * PAD];
  int tid = threadIdx.x;
  int bm = blockIdx.y * 128;
  int k0 = blockIdx.z * KC;
  int lane = tid & 63, w = tid >> 6;
  int wm = (w & 1) * 64, wn = (w >> 1) * 64;
  int l15 = lane & 15, quad = lane >> 4;
  f32x4 zero = {0.f, 0.f, 0.f, 0.f};
  f32x4 acc[4][4];
#pragma unroll
  for (int mt = 0; mt < 4; mt++)
#pragma unroll
    for (int nt = 0; nt < 4; nt++) acc[mt][nt] = zero;

  for (int kt = 0; kt < KC; kt += 32) {
    int kr = tid >> 3;
    int mc = (tid & 7) * 16;
    int k = k0 + kt + kr;
    float mvk = (AMODE == 1) ? mv[k] : 0.f;
#pragma unroll
    for (int q = 0; q < 4; q++) {
      int m0 = mc + q * 4;
      float4 pv = *(const float4*)&P[(size_t)k * C + bm + m0];
      float4 c1 = *(const float4*)&col1[bm + m0];
      float wv[4];
      if (AMODE == 1) {
        wv[0] = pv.x * mvk / (c1.x * pv.x + 1.f);
        wv[1] = pv.y * mvk / (c1.y * pv.y + 1.f);
        wv[2] = pv.z * mvk / (c1.z * pv.z + 1.f);
        wv[3] = pv.w * mvk / (c1.w * pv.w + 1.f);
      } else {
        float4 c2 = *(const float4*)&col2[bm + m0];
        wv[0] = __expf(pv.x - c1.x) / c2.x;
        wv[1] = __expf(pv.y - c1.y) / c2.y;
        wv[2] = __expf(pv.z - c1.z) / c2.z;
        wv[3] = __expf(pv.w - c1.w) / c2.w;
      }
#pragma unroll
      for (int j = 0; j < 4; j++) {
        unsigned short hh = f2bf(wv[j]);
        sAh[(m0 + j) * PAD + kr] = hh;
        sAl[(m0 + j) * PAD + kr] = f2bf(wv[j] - bf2f(hh));
      }
    }
#pragma unroll
    for (int q = 0; q < 2; q++) {
      int f = q * 256 + tid;
      int row = f >> 2, ch = f & 3;
      size_t gb = (size_t)row * N + k0 + kt + ch * 8;
      int ls = row * PAD + ch * 8;
      *(uint4*)&sBh[ls] = *(const uint4*)&Bthi[gb];
      *(uint4*)&sBl[ls] = *(const uint4*)&Btlo[gb];
    }
    __syncthreads();
    bf16x8 ah[4], al[4], bh[4], bl[4];
#pragma unroll
    for (int t = 0; t < 4; t++) {
      int ar = (wm + t * 16 + l15) * PAD + quad * 8;
      ah[t] = *(const bf16x8*)&sAh[ar];
      al[t] = *(const bf16x8*)&sAl[ar];
      int br = (wn + t * 16 + l15) * PAD + quad * 8;
      bh[t] = *(const bf16x8*)&sBh[br];
      bl[t] = *(const bf16x8*)&sBl[br];
    }
#pragma unroll
    for (int mt = 0; mt < 4; mt++)
#pragma unroll
      for (int nt = 0; nt < 4; nt++) {
        acc[mt][nt] = __builtin_amdgcn_mfma_f32_16x16x32_bf16(ah[mt], bh[nt], acc[mt][nt], 0, 0, 0);
        acc[mt][nt] = __builtin_amdgcn_mfma_f32_16x16x32_bf16(ah[mt], bl[nt], acc[mt][nt], 0, 0, 0);
        acc[mt][nt] = __builtin_amdgcn_mfma_f32_16x16x32_bf16(al[mt], bh[nt], acc[mt][nt], 0, 0, 0);
      }
    __syncthreads();
  }
  float* pp = partial + (size_t)blockIdx.z * C * 128;
#pragma unroll
  for (int mt = 0; mt < 4; mt++)
#pragma unroll
    for (int nt = 0; nt < 4; nt++) {
      int col = wn + nt * 16 + l15;
#pragma unroll
      for (int rg = 0; rg < 4; rg++) {
        int row = bm + wm + mt * 16 + quad * 4 + rg;
        pp[(size_t)row * 128 + col] = acc[mt][nt][rg];
      }
    }
}

// ---------------- bf16x3 MFMA linear, 32-row blocks ----------------
template <int EPI>
__global__ __launch_bounds__(256) void k_mfma_lin(
    const float* __restrict__ A, const float* __restrict__ Wt,
    const float* __restrict__ bias, const float* __restrict__ aux,
    float* __restrict__ out) {
  __shared__ __align__(16) unsigned short sAh[32 * PAD];
  __shared__ __align__(16) unsigned short sAl[32 * PAD];
  __shared__ __align__(16) unsigned short sWh[128 * PAD];
  __shared__ __align__(16) unsigned short sWl[128 * PAD];
  int tid = threadIdx.x;
  int bm = blockIdx.y * 32;
  int lane = tid & 63, w = tid >> 6;
  int rt = (w & 1) * 16, ch2 = (w >> 1) * 64;
  int l15 = lane & 15, quad = lane >> 4;
  f32x4 zero = {0.f, 0.f, 0.f, 0.f};
  f32x4 acc[4];
#pragma unroll
  for (int nt = 0; nt < 4; nt++) acc[nt] = zero;

  for (int kt = 0; kt < 128; kt += 32) {
    {
      int arow = tid >> 3, ach = tid & 7;
      float4 av = *(const float4*)&A[(size_t)(bm + arow) * 128 + kt + ach * 4];
      float aa[4] = {av.x, av.y, av.z, av.w};
      int ls = arow * PAD + ach * 4;
#pragma unroll
      for (int c = 0; c < 4; c++) {
        unsigned short hh = f2bf(aa[c]);
        sAh[ls + c] = hh;
        sAl[ls + c] = f2bf(aa[c] - bf2f(hh));
      }
    }
#pragma unroll
    for (int q = 0; q < 4; q++) {
      int f = q * 256 + tid;
      int wrow = f >> 3, wch = f & 7;
      float4 wv = *(const float4*)&Wt[(size_t)wrow * 128 + kt + wch * 4];
      float ww[4] = {wv.x, wv.y, wv.z, wv.w};
      int ls = wrow * PAD + wch * 4;
#pragma unroll
      for (int c = 0; c < 4; c++) {
        unsigned short hh = f2bf(ww[c]);
        sWh[ls + c] = hh;
        sWl[ls + c] = f2bf(ww[c] - bf2f(hh));
      }
    }
    __syncthreads();
    bf16x8 ah, al, bh[4], bl[4];
    {
      int ar = (rt + l15) * PAD + quad * 8;
      ah = *(const bf16x8*)&sAh[ar];
      al = *(const bf16x8*)&sAl[ar];
    }
#pragma unroll
    for (int nt = 0; nt < 4; nt++) {
      int br = (ch2 + nt * 16 + l15) * PAD + quad * 8;
      bh[nt] = *(const bf16x8*)&sWh[br];
      bl[nt] = *(const bf16x8*)&sWl[br];
    }
#pragma unroll
    for (int nt = 0; nt < 4; nt++) {
      acc[nt] = __builtin_amdgcn_mfma_f32_16x16x32_bf16(ah, bh[nt], acc[nt], 0, 0, 0);
      acc[nt] = __builtin_amdgcn_mfma_f32_16x16x32_bf16(ah, bl[nt], acc[nt], 0, 0, 0);
      acc[nt] = __builtin_amdgcn_mfma_f32_16x16x32_bf16(al, bh[nt], acc[nt], 0, 0, 0);
    }
    __syncthreads();
  }
#pragma unroll
  for (int nt = 0; nt < 4; nt++) {
    int col = ch2 + nt * 16 + l15;
    float bv = bias[col];
#pragma unroll
    for (int rg = 0; rg < 4; rg++) {
      int row = bm + rt + quad * 4 + rg;
      size_t off = (size_t)row * 128 + col;
      float v = acc[nt][rg] + bv;
      if (EPI == 0) out[off] = v;
      else if (EPI == 1) out[off] = lrelu(v);
      else if (EPI == 2) out[off] += lrelu(v);
      else out[off] = aux[off] - v;
    }
  }
}

__global__ __launch_bounds__(256) void k_scatter(
    const float* __restrict__ mtv, const int* __restrict__ mtj,
    const float* __restrict__ h, float* __restrict__ hidden2,
    float* __restrict__ colsum_m) {
  int i = blockIdx.x * 4 + (threadIdx.x >> 6);
  int lane = threadIdx.x & 63;
  float h0 = h[(size_t)i * H + lane], h1 = h[(size_t)i * H + 64 + lane];
#pragma unroll
  for (int s = 0; s < 3; s++) {
    float v = mtv[i * 3 + s];
    int j = mtj[i * 3 + s];
    atomicAdd(&hidden2[(size_t)j * H + lane], v * h0);
    atomicAdd(&hidden2[(size_t)j * H + 64 + lane], v * h1);
    if (lane == s) atomicAdd(&colsum_m[j], v);
  }
}

// reduce split-K partials; optional per-row scale (mul) or divisor (div);
// optional bf16 hi/lo pair emission
__global__ __launch_bounds__(256) void k_reduce(
    const float* __restrict__ partial, float* __restrict__ out, int cnt,
    size_t slot, size_t size4, const float* __restrict__ scalem,
    const float* __restrict__ divm, unsigned short* __restrict__ hi,
    unsigned short* __restrict__ lo) {
  size_t idx = (size_t)blockIdx.x * 256 + threadIdx.x;
  if (idx >= size4) return;
  float4 s = {0, 0, 0, 0};
  for (int c = 0; c < cnt; c++) {
    float4 v = *(const float4*)&partial[c * slot + idx * 4];
    s.x += v.x; s.y += v.y; s.z += v.z; s.w += v.w;
  }
  if (scalem) {
    float sc = scalem[idx >> 5];
    s.x *= sc; s.y *= sc; s.z *= sc; s.w *= sc;
  }
  if (divm) {
    float sc = 1.f / divm[idx >> 5];
    s.x *= sc; s.y *= sc; s.z *= sc; s.w *= sc;
  }
  *(float4*)&out[idx * 4] = s;
  if (hi) {
    float vv[4] = {s.x, s.y, s.z, s.w};
    unsigned short h[4], l[4];
#pragma unroll
    for (int c = 0; c < 4; c++) {
      h[c] = f2bf(vv[c]);
      l[c] = f2bf(vv[c] - bf2f(h[c]));
    }
    uint2 ph = {(unsigned)h[0] | ((unsigned)h[1] << 16),
                (unsigned)h[2] | ((unsigned)h[3] << 16)};
    uint2 pl = {(unsigned)l[0] | ((unsigned)l[1] << 16),
                (unsigned)l[2] | ((unsigned)l[3] << 16)};
    *(uint2*)&hi[idx * 4] = ph;
    *(uint2*)&lo[idx * 4] = pl;
  }
}

// ---------------- launch ----------------

extern "C" void kernel_launch(void* const* d_in, const int* in_sizes, int n_in,
                              void* d_out, int out_size, void* d_ws, size_t ws_size,
                              hipStream_t stream) {
  (void)in_sizes; (void)n_in; (void)out_size;
  const float* x   = (const float*)d_in[0];
  const float* cm  = (const float*)d_in[1];
  const float* mv  = (const float*)d_in[2];
  const float* W_ps = (const float*)d_in[3],  *b_ps = (const float*)d_in[4];
  const float* W_psf = (const float*)d_in[5], *b_psf = (const float*)d_in[6];
  const float* W_psb = (const float*)d_in[7], *b_psb = (const float*)d_in[8];
  const float* W_hs = (const float*)d_in[9],  *b_hs = (const float*)d_in[10];
  const float* W_hsf = (const float*)d_in[11], *b_hsf = (const float*)d_in[12];
  const float* W_hsb = (const float*)d_in[13], *b_hsb = (const float*)d_in[14];
  const float* W_in = (const float*)d_in[15], *b_in = (const float*)d_in[16];
  const float* W_out = (const float*)d_in[17], *b_out = (const float*)d_in[18];
  float* out = (float*)d_out;

  float* W = (float*)d_ws;
  size_t o = 0;
  auto alloc = [&](size_t n) { float* p = W + o; o += n; return p; };
  float* colsum_c = alloc(C);
  float* colmax   = alloc(C);
  float* colsumexp= alloc(C);
  float* valid1   = alloc(C);
  float* hnorm_ps = alloc(C);
  float* xnorm    = alloc(N);
  float* diagv    = alloc(N);
  float* colsum_m = alloc(N);
  float* valid2f  = alloc(N);
  float* lsum     = alloc(N);
  float* mtv      = alloc(3 * N);
  int*   mtj      = (int*)alloc(3 * N);
  float* hidden1  = alloc((size_t)C * H);
  float* hidden_ps= alloc((size_t)C * H);
  float* scores   = alloc((size_t)N * C);
  float* ps_pre   = alloc((size_t)N * H);   // later hs_pre
  float* p_shared = alloc((size_t)N * H);   // later h_shared
  float* all_info = alloc((size_t)N * H);
  float* hbuf     = alloc((size_t)N * H);   // h; later indiv (in-place)
  float* hhat     = alloc((size_t)N * H);
  float* hidden2  = alloc((size_t)N * H);
  unsigned short* xhi    = (unsigned short*)alloc((size_t)N * H / 2);
  unsigned short* xlo    = (unsigned short*)alloc((size_t)N * H / 2);
  unsigned short* hhathi = (unsigned short*)alloc((size_t)N * H / 2);
  unsigned short* hhatlo = (unsigned short*)alloc((size_t)N * H / 2);
  unsigned short* h2hi   = (unsigned short*)alloc((size_t)N * H / 2);
  unsigned short* h2lo   = (unsigned short*)alloc((size_t)N * H / 2);
  unsigned short* h1hi   = (unsigned short*)alloc((size_t)C * H / 2);
  unsigned short* h1lo   = (unsigned short*)alloc((size_t)C * H / 2);
  unsigned short* hpshi  = (unsigned short*)alloc((size_t)C * H / 2);
  unsigned short* hpslo  = (unsigned short*)alloc((size_t)C * H / 2);
  unsigned short* cshi   = (unsigned short*)alloc((size_t)N * C / 2);
  unsigned short* cslo   = (unsigned short*)alloc((size_t)N * C / 2);
  unsigned short* hpst_hi= (unsigned short*)alloc((size_t)H * C / 2);
  unsigned short* hpst_lo= (unsigned short*)alloc((size_t)H * C / 2);
  unsigned short* h2t_hi = (unsigned short*)alloc((size_t)H * N / 2);
  unsigned short* h2t_lo = (unsigned short*)alloc((size_t)H * N / 2);
  unsigned short* xt_hi  = (unsigned short*)alloc((size_t)H * N / 2);
  unsigned short* xt_lo  = (unsigned short*)alloc((size_t)H * N / 2);
  float* Sbuf     = alloc((size_t)N * N / 2);   // 32 MB: fp16 S, then bf16 E
  unsigned short* Sh  = (unsigned short*)Sbuf;
  unsigned short* Ehi = (unsigned short*)Sbuf;  // alias: S dead after rowtop
  float* partial  = W + o;
  size_t rem = ws_size / 4 - o;
  int Z = (rem >= (size_t)16 * N * H) ? 16 : 8;
  int KC = 4096 / Z;

  hipMemsetAsync(colsum_c, 0, C * sizeof(float), stream);
  hipMemsetAsync(colsum_m, 0, N * sizeof(float), stream);
  hipMemsetAsync(lsum, 0, N * sizeof(float), stream);
  hipMemsetAsync(hidden2, 0, (size_t)N * H * sizeof(float), stream);

  dim3 blk(256);
  // --- ps branch ---
  k_split<<<dim3(N * H / 1024), blk, 0, stream>>>(x, xhi, xlo);
  k_tsplit<<<dim3(N / 32), blk, 0, stream>>>(x, xt_hi, xt_lo, N);
  k_colsum_s2c<<<dim3(C / 64, 16), dim3(64), 0, stream>>>(cm, mv, colsum_c);
  k_mfma_genA<1><<<dim3(1, C / 128, 32), blk, 0, stream>>>(
      cm, mv, colsum_c, nullptr, xt_hi, xt_lo, partial, N / 32);
  k_reduce<<<dim3(C * H / 4 / 256), blk, 0, stream>>>(
      partial, hidden1, 32, (size_t)C * H, (size_t)C * H / 4, nullptr, nullptr,
      h1hi, h1lo);
  k_valid1<<<dim3(C), dim3(64), 0, stream>>>(hidden1, valid1);
  k_mfma_nt<0><<<dim3(C / 128, N / 128), blk, 0, stream>>>(
      xhi, xlo, h1hi, h1lo, nullptr, scores, nullptr, nullptr, C);
  k_colstats<<<dim3(C), blk, 0, stream>>>(scores, colmax, colsumexp);
  k_mfma_genA<2><<<dim3(1, C / 128, 32), blk, 0, stream>>>(
      scores, nullptr, colmax, colsumexp, xt_hi, xt_lo, partial, N / 32);
  k_reduce<<<dim3(C * H / 4 / 256), blk, 0, stream>>>(
      partial, hidden_ps, 32, (size_t)C * H, (size_t)C * H / 4, valid1, nullptr,
      hpshi, hpslo);
  k_rownorm128<<<dim3(N), dim3(64), 0, stream>>>(x, xnorm);
  k_rownorm128<<<dim3(C), dim3(64), 0, stream>>>(hidden_ps, hnorm_ps);
  k_mfma_nt<0><<<dim3(C / 128, N / 128), blk, 0, stream>>>(
      xhi, xlo, hpshi, hpslo, nullptr, scores, nullptr, nullptr, C);
  k_cs_softmax<<<dim3(N), blk, 0, stream>>>(scores, xnorm, hnorm_ps, valid1,
                                            cshi, cslo);
  k_tsplit<<<dim3(C / 32), blk, 0, stream>>>(hidden_ps, hpst_hi, hpst_lo, C);
  k_mfma_kn<1><<<dim3(1, N / 128, 4), blk, 0, stream>>>(
      cshi, cslo, hpst_hi, hpst_lo, partial, C, C / 4);
  k_reduce<<<dim3(N * H / 4 / 256), blk, 0, stream>>>(
      partial, ps_pre, 4, (size_t)N * H, (size_t)N * H / 4, nullptr, nullptr,
      nullptr, nullptr);
  k_mfma_lin<0><<<dim3(1, N / 32), blk, 0, stream>>>(
      ps_pre, W_ps, b_ps, nullptr, p_shared);
  k_mfma_lin<3><<<dim3(1, N / 32), blk, 0, stream>>>(
      p_shared, W_psb, b_psb, x, hbuf);                      // h = x - p_back
  k_mfma_lin<1><<<dim3(1, N / 32), blk, 0, stream>>>(
      p_shared, W_psf, b_psf, nullptr, all_info);            // out_ps
  // --- hs branch ---
  k_hhat<<<dim3(N), dim3(64), 0, stream>>>(hbuf, hhat, hhathi, hhatlo, diagv);
  k_mfma_nt<2><<<dim3(N / 128, N / 128), blk, 0, stream>>>(
      hhathi, hhatlo, hhathi, hhatlo, nullptr, nullptr, Sh, nullptr, N);
  k_rowtop<<<dim3(N / 4), blk, 0, stream>>>(Sh, hhat, mtv, mtj);
  k_scatter<<<dim3(N / 4), blk, 0, stream>>>(mtv, mtj, hbuf, hidden2, colsum_m);
  k_fin_hidden2<<<dim3(N), dim3(64), 0, stream>>>(hbuf, diagv, colsum_m, hidden2,
                                                  h2hi, h2lo, valid2f);
  k_mfma_nt<3><<<dim3(N / 128, N / 128), blk, 0, stream>>>(
      hhathi, hhatlo, h2hi, h2lo, valid2f, nullptr, Ehi, lsum, N);
  k_tsplit<<<dim3(N / 32), blk, 0, stream>>>(hidden2, h2t_hi, h2t_lo, N);
  k_mfma_kn<0><<<dim3(1, N / 128, Z), blk, 0, stream>>>(
      Ehi, nullptr, h2t_hi, h2t_lo, partial, N, KC);
  k_reduce<<<dim3(N * H / 4 / 256), blk, 0, stream>>>(
      partial, ps_pre, Z, (size_t)N * H, (size_t)N * H / 4, nullptr, lsum,
      nullptr, nullptr);  // hs_pre = U / l
  k_mfma_lin<0><<<dim3(1, N / 32), blk, 0, stream>>>(
      ps_pre, W_hs, b_hs, nullptr, p_shared);                // h_shared
  k_mfma_lin<2><<<dim3(1, N / 32), blk, 0, stream>>>(
      p_shared, W_hsf, b_hsf, nullptr, all_info);            // += out_hs
  k_mfma_lin<3><<<dim3(1, N / 32), blk, 0, stream>>>(
      p_shared, W_hsb, b_hsb, hbuf, hbuf);                   // indiv = h - h_back
  k_mfma_lin<2><<<dim3(1, N / 32), blk, 0, stream>>>(
      hbuf, W_in, b_in, nullptr, all_info);                  // += out_indi
  k_final<<<dim3(N), dim3(64), 0, stream>>>(all_info, W_out, b_out, out);
}